// Round 13
// baseline (223.599 us; speedup 1.0000x reference)
//
#include <hip/hip_runtime.h>
#include <hip/hip_bf16.h>

// ---------------------------------------------------------------------------
// PagedHSTUInferLayer on MI355X (gfx950)
// LN -> GEMM1(bf16 MFMA, BK=64 dbuf global_load_lds, 2-phase pipeline) ->
// HSTU attention (R11 structure, nx merged into hx, by-ref P-pack) ->
// gated LN -> GEMM2(+residual, fp32 out)
//
// R6..R12 lessons: attn's ~192 true regs/thread (VGPR+AGPR unified) cap the
//   CU at 8 waves; 7 structural variants all pinned at ~113us. Pipes sum to
//   ~52% (MFMA 13.5 + VALU 27 + LDS ~11); VALU implied ops ~3x algorithmic
//   need -> register-starved remat. R13 cuts 16 arch regs (nx gone) and the
//   16-reg sa copy; gemm gets the T3-minimum 2-phase prefetch (loads issued
//   BEFORE compute, one vmcnt(0)+barrier per k-step).
// ---------------------------------------------------------------------------

typedef __attribute__((ext_vector_type(8))) short v8s;    // 8 x bf16 (4 VGPR)
typedef __attribute__((ext_vector_type(4))) float v4f;    // 16x16 accumulator
typedef __attribute__((ext_vector_type(16))) float v16f;  // 32x32 accumulator
typedef __attribute__((ext_vector_type(4))) unsigned short v4us;
typedef __attribute__((ext_vector_type(4))) unsigned int v4u;

#define D_HID 512
#define U_DIM 2048
#define NHEAD 4
#define DHEAD 128
#define BATCH 32
#define SEQ   256
#define HIST  2048
#define NTOK  8192
#define ALPHA_ 0.08838834764831845f   // 1/sqrt(128)
#define EPS_   1e-5f

__device__ __forceinline__ unsigned short f2bf(float f) {
  unsigned int u = __float_as_uint(f);
  u += 0x7FFFu + ((u >> 16) & 1u);            // round-to-nearest-even
  return (unsigned short)(u >> 16);
}
__device__ __forceinline__ float bf2f(unsigned short s) {
  return __uint_as_float(((unsigned int)s) << 16);
}
// silu via fast hw reciprocal (harness has no -ffast-math)
__device__ __forceinline__ float siluf(float x) {
  return x * __builtin_amdgcn_rcpf(1.0f + __expf(-x));
}
// packed 2xf32 -> 2xbf16 (v_cvt_pk_bf16_f32), lo in bits 0-15
__device__ __forceinline__ unsigned int cvtpk(float lo, float hi) {
  __hip_bfloat162 h = __float22bfloat162_rn(make_float2(lo, hi));
  union { __hip_bfloat162 h; unsigned int u; } cv; cv.h = h;
  return cv.u;
}

// ---------------------------------------------------------------------------
// LN over D=512 per row -> bf16. 4 waves/block, one row per wave.
// ---------------------------------------------------------------------------
__global__ __launch_bounds__(256) void ln_in_kernel(
    const float* __restrict__ x, const float* __restrict__ w,
    const float* __restrict__ b, unsigned short* __restrict__ out)
{
  int wid = threadIdx.x >> 6, lane = threadIdx.x & 63;
  int row = blockIdx.x * 4 + wid;
  const float* xr = x + (size_t)row * D_HID + lane * 8;
  float4 a0 = *(const float4*)xr;
  float4 a1 = *(const float4*)(xr + 4);
  float v[8] = {a0.x, a0.y, a0.z, a0.w, a1.x, a1.y, a1.z, a1.w};
  float s = 0.f, s2 = 0.f;
#pragma unroll
  for (int j = 0; j < 8; ++j) { s += v[j]; s2 += v[j] * v[j]; }
#pragma unroll
  for (int m = 1; m < 64; m <<= 1) { s += __shfl_xor(s, m, 64); s2 += __shfl_xor(s2, m, 64); }
  float mean = s * (1.f / D_HID);
  float var  = s2 * (1.f / D_HID) - mean * mean;
  float rstd = rsqrtf(var + EPS_);
  const float* wp = w + lane * 8; const float* bp = b + lane * 8;
  float4 w0 = *(const float4*)wp, w1 = *(const float4*)(wp + 4);
  float4 b0 = *(const float4*)bp, b1 = *(const float4*)(bp + 4);
  float wv[8] = {w0.x, w0.y, w0.z, w0.w, w1.x, w1.y, w1.z, w1.w};
  float bv[8] = {b0.x, b0.y, b0.z, b0.w, b1.x, b1.y, b1.z, b1.w};
  v8s o;
#pragma unroll
  for (int j = 0; j < 8; ++j) o[j] = (short)f2bf((v[j] - mean) * rstd * wv[j] + bv[j]);
  *(v8s*)(out + (size_t)row * D_HID + lane * 8) = o;
}

// ---------------------------------------------------------------------------
// gated LN: parallel = u * LN(attn0 + attn1)
// ---------------------------------------------------------------------------
__global__ __launch_bounds__(256) void gated_ln_kernel(
    const float* __restrict__ attn0, const float* __restrict__ attn1,
    const unsigned short* __restrict__ uvqk,
    const float* __restrict__ w, const float* __restrict__ b,
    unsigned short* __restrict__ par)
{
  int wid = threadIdx.x >> 6, lane = threadIdx.x & 63;
  int row = blockIdx.x * 4 + wid;
  size_t off = (size_t)row * D_HID + lane * 8;
  float4 x0 = *(const float4*)(attn0 + off), x1 = *(const float4*)(attn0 + off + 4);
  float4 y0 = *(const float4*)(attn1 + off), y1 = *(const float4*)(attn1 + off + 4);
  float v[8] = {x0.x + y0.x, x0.y + y0.y, x0.z + y0.z, x0.w + y0.w,
                x1.x + y1.x, x1.y + y1.y, x1.z + y1.z, x1.w + y1.w};
  float s = 0.f, s2 = 0.f;
#pragma unroll
  for (int j = 0; j < 8; ++j) { s += v[j]; s2 += v[j] * v[j]; }
#pragma unroll
  for (int m = 1; m < 64; m <<= 1) { s += __shfl_xor(s, m, 64); s2 += __shfl_xor(s2, m, 64); }
  float mean = s * (1.f / D_HID);
  float var  = s2 * (1.f / D_HID) - mean * mean;
  float rstd = rsqrtf(var + EPS_);
  const float* wp = w + lane * 8; const float* bp = b + lane * 8;
  float4 w0 = *(const float4*)wp, w1 = *(const float4*)(wp + 4);
  float4 b0 = *(const float4*)bp, b1 = *(const float4*)(bp + 4);
  float wv[8] = {w0.x, w0.y, w0.z, w0.w, w1.x, w1.y, w1.z, w1.w};
  float bv[8] = {b0.x, b0.y, b0.z, b0.w, b1.x, b1.y, b1.z, b1.w};
  v8s uv = *(const v8s*)(uvqk + (size_t)row * U_DIM + lane * 8);
  v8s o;
#pragma unroll
  for (int j = 0; j < 8; ++j) {
    float u = bf2f((unsigned short)uv[j]);
    o[j] = (short)f2bf(u * ((v[j] - mean) * rstd * wv[j] + bv[j]));
  }
  *(v8s*)(par + (size_t)row * D_HID + lane * 8) = o;
}

// ---------------------------------------------------------------------------
// Transpose fp32 (R x C) -> bf16 (C x R).  32x32 LDS tiles.
// ---------------------------------------------------------------------------
__global__ __launch_bounds__(256) void transpose_w_kernel(
    const float* __restrict__ in, unsigned short* __restrict__ out, int R, int C)
{
  __shared__ float tile[32][33];
  int c0 = blockIdx.x * 32, r0 = blockIdx.y * 32;
  int tr = threadIdx.x >> 3;
  int tc = (threadIdx.x & 7) * 4;
  float4 vv = *(const float4*)(in + (size_t)(r0 + tr) * C + c0 + tc);
  tile[tr][tc + 0] = vv.x; tile[tr][tc + 1] = vv.y;
  tile[tr][tc + 2] = vv.z; tile[tr][tc + 3] = vv.w;
  __syncthreads();
  v4us o;
#pragma unroll
  for (int j = 0; j < 4; ++j) o[j] = f2bf(tile[tc + j][tr]);
  *(v4us*)(out + (size_t)(c0 + tr) * R + r0 + tc) = o;
}

// ---------------------------------------------------------------------------
// bf16 GEMM, 128x128 tile, BK=64, 4 waves (2x2 of 64x64), 16x16x32 MFMA.
// Double-buffered global_load_lds (T3-minimum 2-phase): STAGE(t+1) issued
// BEFORE compute(t); one vmcnt(0)+barrier per k-step.  LINEAR LDS dest with
// PRE-SWIZZLED global source col ((tid&7)*8) ^ ((row&7)<<3); reads apply
// the same XOR -> 2-way (free) bank access.
// EPI 0: out_bf16 = silu(acc + bias[n])   (q columns additionally * ALPHA)
// EPI 1: out_f32 = acc + resid[m][n].
// ---------------------------------------------------------------------------
template <int EPI>
__global__ __launch_bounds__(256) void gemm_kernel(
    const unsigned short* __restrict__ A, const unsigned short* __restrict__ Bt,
    int K, int N,
    const float* __restrict__ bias, const float* __restrict__ resid,
    unsigned short* __restrict__ outb, float* __restrict__ outf)
{
  __shared__ unsigned short Al[2][128 * 64];   // dbuf, linear dest (gload_lds)
  __shared__ unsigned short Bl[2][128 * 64];
  int m0 = blockIdx.x * 128, n0 = blockIdx.y * 128;
  int tid = threadIdx.x, lane = tid & 63, wid = tid >> 6;
  int wr = wid >> 1, wc = wid & 1;
  int lr = lane & 15, lg = lane >> 4;
  int rkey = (lr & 7) << 3;                 // read-side swizzle (shorts)

  v4f acc[4][4];
#pragma unroll
  for (int i = 0; i < 4; ++i)
#pragma unroll
    for (int j = 0; j < 4; ++j) acc[i][j] = (v4f){0.f, 0.f, 0.f, 0.f};

  // staging: thread t covers rows {c*32 + (t>>3)}, source col pre-swizzled
  int srow = tid >> 3;                      // 0..31
  int scol = ((tid & 7) * 8) ^ ((srow & 7) << 3);
  const unsigned short* gA = A  + (size_t)(m0 + srow) * K + scol;
  const unsigned short* gB = Bt + (size_t)(n0 + srow) * K + scol;

  auto STAGE = [&](int buf, int k0) {
#pragma unroll
    for (int c = 0; c < 4; ++c) {
      __builtin_amdgcn_global_load_lds(
          (const __attribute__((address_space(1))) unsigned int*)(gA + (size_t)(c * 32) * K + k0),
          (__attribute__((address_space(3))) unsigned int*)&Al[buf][c * 2048 + wid * 512], 16, 0, 0);
      __builtin_amdgcn_global_load_lds(
          (const __attribute__((address_space(1))) unsigned int*)(gB + (size_t)(c * 32) * K + k0),
          (__attribute__((address_space(3))) unsigned int*)&Bl[buf][c * 2048 + wid * 512], 16, 0, 0);
    }
  };

  const int NTk = K >> 6;                   // 8 (gemm1) / 8 (gemm2)
  STAGE(0, 0);
  asm volatile("s_waitcnt vmcnt(0)" ::: "memory");
  __syncthreads();

  for (int t = 0; t < NTk; ++t) {
    int cur = t & 1;
    if (t + 1 < NTk) STAGE(cur ^ 1, (t + 1) * 64);   // prefetch next k-step
#pragma unroll
    for (int kk = 0; kk < 2; ++kk) {
      v8s af[4], bf[4];
#pragma unroll
      for (int mt = 0; mt < 4; ++mt)
        af[mt] = *(const v8s*)&Al[cur][(wr * 64 + mt * 16 + lr) * 64 + ((kk * 32 + lg * 8) ^ rkey)];
#pragma unroll
      for (int nt = 0; nt < 4; ++nt)
        bf[nt] = *(const v8s*)&Bl[cur][(wc * 64 + nt * 16 + lr) * 64 + ((kk * 32 + lg * 8) ^ rkey)];
#pragma unroll
      for (int mt = 0; mt < 4; ++mt)
#pragma unroll
        for (int nt = 0; nt < 4; ++nt)
          acc[mt][nt] = __builtin_amdgcn_mfma_f32_16x16x32_bf16(af[mt], bf[nt], acc[mt][nt], 0, 0, 0);
    }
    if (t + 1 < NTk) {
      asm volatile("s_waitcnt vmcnt(0)" ::: "memory");
      __syncthreads();
    }
  }

#pragma unroll
  for (int nt = 0; nt < 4; ++nt) {
    int col = n0 + wc * 64 + nt * 16 + lr;
    float bi = 0.f;
    if constexpr (EPI == 0) bi = bias[col];
#pragma unroll
    for (int mt = 0; mt < 4; ++mt) {
      int row0 = m0 + wr * 64 + mt * 16 + lg * 4;
#pragma unroll
      for (int r = 0; r < 4; ++r) {
        float xv = acc[mt][nt][r];
        if constexpr (EPI == 0) {
          float rv = siluf(xv + bi);
          if ((unsigned)(col - 2 * D_HID) < (unsigned)D_HID) rv *= ALPHA_;  // q cols
          outb[(size_t)(row0 + r) * N + col] = f2bf(rv);
        } else {
          outf[(size_t)(row0 + r) * N + col] = xv + resid[(size_t)(row0 + r) * N + col];
        }
      }
    }
  }
}

// ---------------------------------------------------------------------------
// HSTU attention (R11 structure, reg-pressure trimmed), 2-way t-split,
// 32x32x16 MFMA, in-register P.
// grid = (q 2)<<7 | (b 32)<<2 | (n 4) = 256 blocks of 512 threads (8 waves).
// Wave w owns q rows w*32 + (lane&31).  18 kv tiles of 64 per block.
//
// QK^T swapped: mfma(K, Q) -> D[t][s], col = s = lane&31.  tt=0/tt=1 rows
// share the same swizzle key, interleaved chains (kf1 = kf0 addr + 4096).
// P packed in regs via cvt_pk + __shfl_xor(32) (by-ref lambda, no sa copy);
// never touches LDS.  New-kv staging reuses hx float4 slots (nx removed).
// LDS: Kl[2][64][128] swizzle col^=((t&7)<<3);  Vt[2][128][64] swizzle
// col^=(((d>>3)^d)&7)<<3 -> conflict-free ds_read_b128, ~2-way writes.
// ---------------------------------------------------------------------------
__global__ __launch_bounds__(512, 2) void attn_kernel(
    const float* __restrict__ histK, const float* __restrict__ histV,
    const unsigned short* __restrict__ uvqk, float* __restrict__ attn_out)
{
  __shared__ __align__(16) unsigned short Kl[2 * 64 * 128];   // [buf][t][d^swz]
  __shared__ __align__(16) unsigned short Vt[2 * 128 * 64];   // [buf][d][t^swz]

  int bid = blockIdx.x;
  int q   = bid >> 7;
  int b   = (bid >> 2) & 31;
  int n   = bid & 3;
  int tbase0 = q * 1152;
  const int NT = 18;

  int tid = threadIdx.x, lane = tid & 63, w = tid >> 6;
  int l5 = lane & 31;
  int hi = lane >> 5;            // 0 / 1
  int hi8 = hi * 8;
  int sq = w * 32 + l5;          // this lane's query row within SEQ

  // Q fragments (B-operand): lane holds Q[s=l5][k = ks*16 + hi*8 + j]
  v8s qf[8];
  {
    const unsigned short* qp = uvqk + (size_t)(b * SEQ + sq) * U_DIM
                               + 2 * D_HID + n * DHEAD + hi8;
#pragma unroll
    for (int ks = 0; ks < 8; ++ks) qf[ks] = *(const v8s*)(qp + ks * 16);
  }

  v16f oacc[4];
#pragma unroll
  for (int i = 0; i < 4; ++i)
#pragma unroll
    for (int r = 0; r < 16; ++r) oacc[i][r] = 0.f;

  int m     = tid & 15;
  int std0  = m * 8;            // staging d offset (8 contiguous)
  int strow = tid >> 4;         // staging t-pair index (0..31)

  const float* kbase = histK + (((size_t)b * HIST) * NHEAD + n) * DHEAD + std0;
  const float* vbase = histV + (((size_t)b * HIST) * NHEAD + n) * DHEAD + std0;
  const unsigned short* nkbase = uvqk + (size_t)(b * SEQ) * U_DIM + 3 * D_HID + n * DHEAD + std0;
  const unsigned short* nvbase = uvqk + (size_t)(b * SEQ) * U_DIM + 1 * D_HID + n * DHEAD + std0;

  // staging registers (next tile in flight); new-kv path reuses slots 0,2
  float4 hx[2][4];              // hist: [p][k0,k1,v0,v1]
  int isnew_r = 0;

  auto stage_load = [&](int kt) {
    int tb = tbase0 + kt * 64;
    if (tb < HIST) {
      isnew_r = 0;
#pragma unroll
      for (int p = 0; p < 2; ++p) {
        unsigned off = ((unsigned)(tb + 2 * strow + p)) << 9;   // *512 floats
        hx[p][0] = *(const float4*)(kbase + off);
        hx[p][1] = *(const float4*)(kbase + off + 4);
        hx[p][2] = *(const float4*)(vbase + off);
        hx[p][3] = *(const float4*)(vbase + off + 4);
      }
    } else {
      isnew_r = 1;
#pragma unroll
      for (int p = 0; p < 2; ++p) {
        unsigned off = ((unsigned)(tb - HIST + 2 * strow + p)) << 11;  // *2048 shorts
        hx[p][0] = *(const float4*)(const void*)(nkbase + off);
        hx[p][2] = *(const float4*)(const void*)(nvbase + off);
      }
    }
  };

  auto stage_store = [&](int buf) {
    unsigned short* Kb = &Kl[buf * 8192];
    unsigned short* Vb = &Vt[buf * 8192];
    int t0 = 2 * strow;
    if (!isnew_r) {
#pragma unroll
      for (int p = 0; p < 2; ++p) {
        int t = t0 + p;
        v4u kp;
        kp[0] = cvtpk(hx[p][0].x, hx[p][0].y);
        kp[1] = cvtpk(hx[p][0].z, hx[p][0].w);
        kp[2] = cvtpk(hx[p][1].x, hx[p][1].y);
        kp[3] = cvtpk(hx[p][1].z, hx[p][1].w);
        *(v4u*)&Kb[t * 128 + (std0 ^ ((t & 7) << 3))] = kp;
      }
      float v0[8] = {hx[0][2].x, hx[0][2].y, hx[0][2].z, hx[0][2].w,
                     hx[0][3].x, hx[0][3].y, hx[0][3].z, hx[0][3].w};
      float v1[8] = {hx[1][2].x, hx[1][2].y, hx[1][2].z, hx[1][2].w,
                     hx[1][3].x, hx[1][3].y, hx[1][3].z, hx[1][3].w};
#pragma unroll
      for (int j = 0; j < 8; ++j) {
        int d = std0 + j;
        int col = t0 ^ ((((d >> 3) ^ d) & 7) << 3);
        *(unsigned int*)&Vb[d * 64 + col] = cvtpk(v0[j], v1[j]);
      }
    } else {
      union { float4 f; v8s s; } ck0, ck1, cv0, cv1;
      ck0.f = hx[0][0]; ck1.f = hx[1][0];
      cv0.f = hx[0][2]; cv1.f = hx[1][2];
#pragma unroll
      for (int p = 0; p < 2; ++p) {
        int t = t0 + p;
        *(v8s*)&Kb[t * 128 + (std0 ^ ((t & 7) << 3))] = p ? ck1.s : ck0.s;
      }
#pragma unroll
      for (int j = 0; j < 8; ++j) {
        int d = std0 + j;
        int col = t0 ^ ((((d >> 3) ^ d) & 7) << 3);
        unsigned int pk = (unsigned int)(unsigned short)cv0.s[j]
                        | ((unsigned int)(unsigned short)cv1.s[j] << 16);
        *(unsigned int*)&Vb[d * 64 + col] = pk;
      }
    }
  };

  // prologue: tile 0 into buf0; tile 1 loaded to regs
  stage_load(0);
  stage_store(0);
  stage_load(1);
  __syncthreads();

  for (int kt = 0; kt < NT; ++kt) {
    int cur = kt & 1;
    if (kt + 1 < NT) stage_store(cur ^ 1);   // tile kt+1 -> other buffer
    if (kt + 2 < NT) stage_load(kt + 2);     // issue tile kt+2 global loads

    int tb = tbase0 + kt * 64;
    bool masked = (tb >= HIST);              // tile in new-token range
    const unsigned short* Kb = &Kl[cur * 8192];
    const unsigned short* Vb = &Vt[cur * 8192];

    __builtin_amdgcn_s_setprio(1);

    // ---- QK^T swapped (32x32x16): two interleaved chains (tt=0, tt=1) ----
    v8s pb[4];                               // PV B-fragments, ks = 0..3
    {
      v16f sa0, sa1;
#pragma unroll
      for (int r = 0; r < 16; ++r) { sa0[r] = 0.f; sa1[r] = 0.f; }
      int kx = (l5 & 7) << 3;                // same key for both tt rows
      int krow = l5 * 128;
#pragma unroll
      for (int ks = 0; ks < 8; ++ks) {
        int off = (ks * 16 + hi8) ^ kx;
        v8s kf0 = *(const v8s*)&Kb[krow + off];          // t row l5
        v8s kf1 = *(const v8s*)&Kb[krow + 4096 + off];   // t row 32+l5
        sa0 = __builtin_amdgcn_mfma_f32_32x32x16_bf16(kf0, qf[ks], sa0, 0, 0, 0);
        sa1 = __builtin_amdgcn_mfma_f32_32x32x16_bf16(kf1, qf[ks], sa1, 0, 0, 0);
      }
      // pack by reference: no 16-reg sa copy
      auto packP = [&](const v16f& sa, int tt) {
        unsigned e[8];
        if (masked) {
          int thr = sq - (tb - HIST) - tt * 32 - 4 * hi;   // keep if tl <= thr
#pragma unroll
          for (int i = 0; i < 8; ++i) {
            int r0 = 2 * i, r1 = 2 * i + 1;
            int tl0 = (r0 & 3) + 8 * (r0 >> 2);
            int tl1 = (r1 & 3) + 8 * (r1 >> 2);
            float p0 = (tl0 <= thr) ? siluf(sa[r0]) : 0.f;
            float p1 = (tl1 <= thr) ? siluf(sa[r1]) : 0.f;
            e[i] = cvtpk(p0, p1);
          }
        } else {
#pragma unroll
          for (int i = 0; i < 8; ++i) e[i] = cvtpk(siluf(sa[2 * i]), siluf(sa[2 * i + 1]));
        }
#pragma unroll
        for (int h = 0; h < 2; ++h) {
          unsigned a0 = e[h * 4 + 0], a1 = e[h * 4 + 1];
          unsigned b0 = e[h * 4 + 2], b1 = e[h * 4 + 3];
          unsigned x0 = (unsigned)__shfl_xor((int)a0, 32, 64);
          unsigned x1 = (unsigned)__shfl_xor((int)a1, 32, 64);
          unsigned x2 = (unsigned)__shfl_xor((int)b0, 32, 64);
          unsigned x3 = (unsigned)__shfl_xor((int)b1, 32, 64);
          union { unsigned u[4]; v8s s; } U;
          U.u[0] = hi ? x2 : a0;
          U.u[1] = hi ? x3 : a1;
          U.u[2] = hi ? b0 : x0;
          U.u[3] = hi ? b1 : x1;
          pb[tt * 2 + h] = U.s;
        }
      };
      packP(sa0, 0);
      packP(sa1, 1);
    }

    // ---- PV: oacc[d][s] += V^T . P^T  (A = Vt rows, B = pb, all in regs) ----
#pragma unroll
    for (int ks = 0; ks < 4; ++ks) {
#pragma unroll
      for (int dt4 = 0; dt4 < 4; ++dt4) {
        int d = dt4 * 32 + l5;
        int col = (ks * 16 + hi8) ^ ((((d >> 3) ^ d) & 7) << 3);
        v8s vf = *(const v8s*)&Vb[d * 64 + col];
        oacc[dt4] = __builtin_amdgcn_mfma_f32_32x32x16_bf16(vf, pb[ks], oacc[dt4], 0, 0, 0);
      }
    }
    __builtin_amdgcn_s_setprio(0);

    if (kt + 1 < NT) __syncthreads();       // buf^1 written by all; cur free
  }

  // ---- epilogue: D[d][s]: col = s = l5 (one q-row per lane), row = d via
  // (r&3)+8*(r>>2)+4*hi -> regs 4g..4g+3 are 4 consecutive d -> float4 ----
  {
    float* op = attn_out + (size_t)q * ((size_t)NTOK * D_HID)
              + (size_t)(b * SEQ + sq) * D_HID + n * DHEAD + 4 * hi;
#pragma unroll
    for (int dt4 = 0; dt4 < 4; ++dt4) {
#pragma unroll
      for (int g = 0; g < 4; ++g) {
        float4 o4 = make_float4(oacc[dt4][4 * g + 0], oacc[dt4][4 * g + 1],
                                oacc[dt4][4 * g + 2], oacc[dt4][4 * g + 3]);
        *(float4*)(op + dt4 * 32 + 8 * g) = o4;
      }
    }
  }
}

// ---------------------------------------------------------------------------
extern "C" void kernel_launch(void* const* d_in, const int* in_sizes, int n_in,
                              void* d_out, int out_size, void* d_ws, size_t ws_size,
                              hipStream_t stream)
{
  (void)in_sizes; (void)n_in; (void)out_size; (void)ws_size;

  const float* layer_input = (const float*)d_in[0];
  const float* hist_k   = (const float*)d_in[1];
  const float* hist_v   = (const float*)d_in[2];
  const float* ln_in_w  = (const float*)d_in[3];
  const float* ln_in_b  = (const float*)d_in[4];
  const float* W_uvqk   = (const float*)d_in[5];
  const float* b_uvqk   = (const float*)d_in[6];
  const float* ln_out_w = (const float*)d_in[7];
  const float* ln_out_b = (const float*)d_in[8];
  const float* W_proj   = (const float*)d_in[9];
  float* out = (float*)d_out;

  // workspace layout (x_bf dead after gemm1; attn1 written by attn -> share):
  char* ws = (char*)d_ws;
  unsigned short* uvqk    = (unsigned short*)(ws);                  // [ 0,32) MiB
  float*          attn0   = (float*)         (ws + (32u << 20));    // [32,48)
  float*          attn1   = (float*)         (ws + (48u << 20));    // [48,64)
  unsigned short* x_bf    = (unsigned short*)(ws + (48u << 20));    // [48,56) (dead before attn)
  unsigned short* par     = (unsigned short*)(ws + (64u << 20));    // [64,72)
  unsigned short* wt_uvqk = (unsigned short*)(ws + (72u << 20));    // [72,74)
  unsigned short* wt_proj = (unsigned short*)(ws + (74u << 20));    // [74,74.5)

  ln_in_kernel<<<dim3(2048), dim3(256), 0, stream>>>(layer_input, ln_in_w, ln_in_b, x_bf);
  transpose_w_kernel<<<dim3(64, 16), dim3(256), 0, stream>>>(W_uvqk, wt_uvqk, 512, 2048);
  transpose_w_kernel<<<dim3(16, 16), dim3(256), 0, stream>>>(W_proj, wt_proj, 512, 512);
  gemm_kernel<0><<<dim3(64, 16), dim3(256), 0, stream>>>(x_bf, wt_uvqk, 512, 2048,
                                                         b_uvqk, nullptr, uvqk, nullptr);
  attn_kernel<<<dim3(256), dim3(512), 0, stream>>>(hist_k, hist_v, uvqk, attn0);
  gated_ln_kernel<<<dim3(2048), dim3(256), 0, stream>>>(attn0, attn1, uvqk, ln_out_w, ln_out_b, par);
  gemm_kernel<1><<<dim3(64, 4), dim3(256), 0, stream>>>(par, wt_proj, 512, 512,
                                                        nullptr, layer_input, nullptr, out);
}

// Round 14
// 156.836 us; speedup vs baseline: 1.4257x; 1.4257x over previous
//
#include <hip/hip_runtime.h>
#include <hip/hip_bf16.h>

// ---------------------------------------------------------------------------
// PagedHSTUInferLayer on MI355X (gfx950)
// LN -> GEMM1(bf16 MFMA, BK=64 global_load_lds + both-sides swizzle) ->
// HSTU attention (R6 structure + interleaved QK chains) -> gated LN ->
// GEMM2(+residual, fp32 out)
//
// R14 = byte-exact restore of R11 (158.1 us, best verified).
// R13 lesson (3rd time: R2, R9, R13): codegen is on a knife-edge at
//   128 VGPR / zero spill. "Equivalent" source rewrites (lambda pack,
//   float4-reinterpret staging, gemm dbuf) perturb allocation -> spill
//   (VGPR 108, WRITE 295MB, attn 167us) or occupancy loss (gemm 64KB dbuf).
// attn pinned at ~113us across 8 structural variants; its ~192 true
//   regs/thread (VGPR+AGPR unified) cap the CU at 8 waves and every
//   occupancy-raising attempt spilled. Do not touch without new evidence.
// ---------------------------------------------------------------------------

typedef __attribute__((ext_vector_type(8))) short v8s;    // 8 x bf16 (4 VGPR)
typedef __attribute__((ext_vector_type(4))) float v4f;    // 16x16 accumulator
typedef __attribute__((ext_vector_type(16))) float v16f;  // 32x32 accumulator
typedef __attribute__((ext_vector_type(4))) unsigned short v4us;
typedef __attribute__((ext_vector_type(4))) unsigned int v4u;

#define D_HID 512
#define U_DIM 2048
#define NHEAD 4
#define DHEAD 128
#define BATCH 32
#define SEQ   256
#define HIST  2048
#define NTOK  8192
#define ALPHA_ 0.08838834764831845f   // 1/sqrt(128)
#define EPS_   1e-5f

__device__ __forceinline__ unsigned short f2bf(float f) {
  unsigned int u = __float_as_uint(f);
  u += 0x7FFFu + ((u >> 16) & 1u);            // round-to-nearest-even
  return (unsigned short)(u >> 16);
}
__device__ __forceinline__ float bf2f(unsigned short s) {
  return __uint_as_float(((unsigned int)s) << 16);
}
// silu via fast hw reciprocal (harness has no -ffast-math; a plain '/'
// emits the full IEEE div sequence)
__device__ __forceinline__ float siluf(float x) {
  return x * __builtin_amdgcn_rcpf(1.0f + __expf(-x));
}
// packed 2xf32 -> 2xbf16 (v_cvt_pk_bf16_f32), lo in bits 0-15
__device__ __forceinline__ unsigned int cvtpk(float lo, float hi) {
  __hip_bfloat162 h = __float22bfloat162_rn(make_float2(lo, hi));
  union { __hip_bfloat162 h; unsigned int u; } cv; cv.h = h;
  return cv.u;
}

// ---------------------------------------------------------------------------
// LN over D=512 per row -> bf16. 4 waves/block, one row per wave.
// ---------------------------------------------------------------------------
__global__ __launch_bounds__(256) void ln_in_kernel(
    const float* __restrict__ x, const float* __restrict__ w,
    const float* __restrict__ b, unsigned short* __restrict__ out)
{
  int wid = threadIdx.x >> 6, lane = threadIdx.x & 63;
  int row = blockIdx.x * 4 + wid;
  const float* xr = x + (size_t)row * D_HID + lane * 8;
  float4 a0 = *(const float4*)xr;
  float4 a1 = *(const float4*)(xr + 4);
  float v[8] = {a0.x, a0.y, a0.z, a0.w, a1.x, a1.y, a1.z, a1.w};
  float s = 0.f, s2 = 0.f;
#pragma unroll
  for (int j = 0; j < 8; ++j) { s += v[j]; s2 += v[j] * v[j]; }
#pragma unroll
  for (int m = 1; m < 64; m <<= 1) { s += __shfl_xor(s, m, 64); s2 += __shfl_xor(s2, m, 64); }
  float mean = s * (1.f / D_HID);
  float var  = s2 * (1.f / D_HID) - mean * mean;
  float rstd = rsqrtf(var + EPS_);
  const float* wp = w + lane * 8; const float* bp = b + lane * 8;
  float4 w0 = *(const float4*)wp, w1 = *(const float4*)(wp + 4);
  float4 b0 = *(const float4*)bp, b1 = *(const float4*)(bp + 4);
  float wv[8] = {w0.x, w0.y, w0.z, w0.w, w1.x, w1.y, w1.z, w1.w};
  float bv[8] = {b0.x, b0.y, b0.z, b0.w, b1.x, b1.y, b1.z, b1.w};
  v8s o;
#pragma unroll
  for (int j = 0; j < 8; ++j) o[j] = (short)f2bf((v[j] - mean) * rstd * wv[j] + bv[j]);
  *(v8s*)(out + (size_t)row * D_HID + lane * 8) = o;
}

// ---------------------------------------------------------------------------
// gated LN: parallel = u * LN(attn0 + attn1)
// ---------------------------------------------------------------------------
__global__ __launch_bounds__(256) void gated_ln_kernel(
    const float* __restrict__ attn0, const float* __restrict__ attn1,
    const unsigned short* __restrict__ uvqk,
    const float* __restrict__ w, const float* __restrict__ b,
    unsigned short* __restrict__ par)
{
  int wid = threadIdx.x >> 6, lane = threadIdx.x & 63;
  int row = blockIdx.x * 4 + wid;
  size_t off = (size_t)row * D_HID + lane * 8;
  float4 x0 = *(const float4*)(attn0 + off), x1 = *(const float4*)(attn0 + off + 4);
  float4 y0 = *(const float4*)(attn1 + off), y1 = *(const float4*)(attn1 + off + 4);
  float v[8] = {x0.x + y0.x, x0.y + y0.y, x0.z + y0.z, x0.w + y0.w,
                x1.x + y1.x, x1.y + y1.y, x1.z + y1.z, x1.w + y1.w};
  float s = 0.f, s2 = 0.f;
#pragma unroll
  for (int j = 0; j < 8; ++j) { s += v[j]; s2 += v[j] * v[j]; }
#pragma unroll
  for (int m = 1; m < 64; m <<= 1) { s += __shfl_xor(s, m, 64); s2 += __shfl_xor(s2, m, 64); }
  float mean = s * (1.f / D_HID);
  float var  = s2 * (1.f / D_HID) - mean * mean;
  float rstd = rsqrtf(var + EPS_);
  const float* wp = w + lane * 8; const float* bp = b + lane * 8;
  float4 w0 = *(const float4*)wp, w1 = *(const float4*)(wp + 4);
  float4 b0 = *(const float4*)bp, b1 = *(const float4*)(bp + 4);
  float wv[8] = {w0.x, w0.y, w0.z, w0.w, w1.x, w1.y, w1.z, w1.w};
  float bv[8] = {b0.x, b0.y, b0.z, b0.w, b1.x, b1.y, b1.z, b1.w};
  v8s uv = *(const v8s*)(uvqk + (size_t)row * U_DIM + lane * 8);
  v8s o;
#pragma unroll
  for (int j = 0; j < 8; ++j) {
    float u = bf2f((unsigned short)uv[j]);
    o[j] = (short)f2bf(u * ((v[j] - mean) * rstd * wv[j] + bv[j]));
  }
  *(v8s*)(par + (size_t)row * D_HID + lane * 8) = o;
}

// ---------------------------------------------------------------------------
// Transpose fp32 (R x C) -> bf16 (C x R).  32x32 LDS tiles.
// ---------------------------------------------------------------------------
__global__ __launch_bounds__(256) void transpose_w_kernel(
    const float* __restrict__ in, unsigned short* __restrict__ out, int R, int C)
{
  __shared__ float tile[32][33];
  int c0 = blockIdx.x * 32, r0 = blockIdx.y * 32;
  int tr = threadIdx.x >> 3;
  int tc = (threadIdx.x & 7) * 4;
  float4 vv = *(const float4*)(in + (size_t)(r0 + tr) * C + c0 + tc);
  tile[tr][tc + 0] = vv.x; tile[tr][tc + 1] = vv.y;
  tile[tr][tc + 2] = vv.z; tile[tr][tc + 3] = vv.w;
  __syncthreads();
  v4us o;
#pragma unroll
  for (int j = 0; j < 4; ++j) o[j] = f2bf(tile[tc + j][tr]);
  *(v4us*)(out + (size_t)(c0 + tr) * R + r0 + tc) = o;
}

// ---------------------------------------------------------------------------
// bf16 GEMM, 128x128 tile, BK=64, 4 waves (2x2 of 64x64), 16x16x32 MFMA.
// Staging via global_load_lds width-16 into LINEAR LDS with PRE-SWIZZLED
// global source col ((tid&7)*8) ^ ((row&7)<<3); reads apply the same XOR
// -> 2-way (free) bank access.  8 k-steps (half the barriers of BK=32).
// EPI 0: out_bf16 = silu(acc + bias[n])   (q columns additionally * ALPHA)
// EPI 1: out_f32 = acc + resid[m][n].
// ---------------------------------------------------------------------------
template <int EPI>
__global__ __launch_bounds__(256) void gemm_kernel(
    const unsigned short* __restrict__ A, const unsigned short* __restrict__ Bt,
    int K, int N,
    const float* __restrict__ bias, const float* __restrict__ resid,
    unsigned short* __restrict__ outb, float* __restrict__ outf)
{
  __shared__ unsigned short Al[128 * 64];   // linear dest (gload_lds)
  __shared__ unsigned short Bl[128 * 64];
  int m0 = blockIdx.x * 128, n0 = blockIdx.y * 128;
  int tid = threadIdx.x, lane = tid & 63, wid = tid >> 6;
  int wr = wid >> 1, wc = wid & 1;
  int lr = lane & 15, lg = lane >> 4;
  int rkey = (lr & 7) << 3;                 // read-side swizzle (shorts)

  v4f acc[4][4];
#pragma unroll
  for (int i = 0; i < 4; ++i)
#pragma unroll
    for (int j = 0; j < 4; ++j) acc[i][j] = (v4f){0.f, 0.f, 0.f, 0.f};

  // staging: thread t covers rows {c*32 + (t>>3)}, source col pre-swizzled
  int srow = tid >> 3;                      // 0..31
  int scol = ((tid & 7) * 8) ^ ((srow & 7) << 3);
  const unsigned short* gA = A  + (size_t)(m0 + srow) * K + scol;
  const unsigned short* gB = Bt + (size_t)(n0 + srow) * K + scol;

  for (int k0 = 0; k0 < K; k0 += 64) {
#pragma unroll
    for (int c = 0; c < 4; ++c) {
      __builtin_amdgcn_global_load_lds(
          (const __attribute__((address_space(1))) unsigned int*)(gA + (size_t)(c * 32) * K + k0),
          (__attribute__((address_space(3))) unsigned int*)&Al[c * 2048 + wid * 512], 16, 0, 0);
      __builtin_amdgcn_global_load_lds(
          (const __attribute__((address_space(1))) unsigned int*)(gB + (size_t)(c * 32) * K + k0),
          (__attribute__((address_space(3))) unsigned int*)&Bl[c * 2048 + wid * 512], 16, 0, 0);
    }
    asm volatile("s_waitcnt vmcnt(0)" ::: "memory");
    __syncthreads();
#pragma unroll
    for (int kk = 0; kk < 2; ++kk) {
      v8s af[4], bf[4];
#pragma unroll
      for (int mt = 0; mt < 4; ++mt)
        af[mt] = *(const v8s*)&Al[(wr * 64 + mt * 16 + lr) * 64 + ((kk * 32 + lg * 8) ^ rkey)];
#pragma unroll
      for (int nt = 0; nt < 4; ++nt)
        bf[nt] = *(const v8s*)&Bl[(wc * 64 + nt * 16 + lr) * 64 + ((kk * 32 + lg * 8) ^ rkey)];
#pragma unroll
      for (int mt = 0; mt < 4; ++mt)
#pragma unroll
        for (int nt = 0; nt < 4; ++nt)
          acc[mt][nt] = __builtin_amdgcn_mfma_f32_16x16x32_bf16(af[mt], bf[nt], acc[mt][nt], 0, 0, 0);
    }
    __syncthreads();
  }

#pragma unroll
  for (int nt = 0; nt < 4; ++nt) {
    int col = n0 + wc * 64 + nt * 16 + lr;
    float bi = 0.f;
    if constexpr (EPI == 0) bi = bias[col];
#pragma unroll
    for (int mt = 0; mt < 4; ++mt) {
      int row0 = m0 + wr * 64 + mt * 16 + lg * 4;
#pragma unroll
      for (int r = 0; r < 4; ++r) {
        float xv = acc[mt][nt][r];
        if constexpr (EPI == 0) {
          float rv = siluf(xv + bi);
          if ((unsigned)(col - 2 * D_HID) < (unsigned)D_HID) rv *= ALPHA_;  // q cols
          outb[(size_t)(row0 + r) * N + col] = f2bf(rv);
        } else {
          outf[(size_t)(row0 + r) * N + col] = xv + resid[(size_t)(row0 + r) * N + col];
        }
      }
    }
  }
}

// ---------------------------------------------------------------------------
// HSTU attention (R6 structure, interleaved QK chains), 2-way t-split,
// 32x32x16 MFMA, in-register P.
// grid = (q 2)<<7 | (b 32)<<2 | (n 4) = 256 blocks of 512 threads (8 waves).
// Wave w owns q rows w*32 + (lane&31).  18 kv tiles of 64 per block.
//
// QK^T swapped: mfma(K, Q) -> D[t][s], col = s = lane&31.  tt=0/tt=1 rows
// share the same swizzle key ((32+l5)&7 == l5&7), so both chains run
// interleaved in one ks loop (kf1 = kf0 addr + 4096) -> 2 independent
// 8-MFMA chains instead of one serial 16-chain.  P packed in regs via
// cvt_pk + __shfl_xor(32); never touches LDS.
// LDS: Kl[2][64][128] swizzle col^=((t&7)<<3);  Vt[2][128][64] swizzle
// col^=(((d>>3)^d)&7)<<3 -> conflict-free ds_read_b128, ~2-way writes.
// ---------------------------------------------------------------------------
__global__ __launch_bounds__(512, 2) void attn_kernel(
    const float* __restrict__ histK, const float* __restrict__ histV,
    const unsigned short* __restrict__ uvqk, float* __restrict__ attn_out)
{
  __shared__ __align__(16) unsigned short Kl[2 * 64 * 128];   // [buf][t][d^swz]
  __shared__ __align__(16) unsigned short Vt[2 * 128 * 64];   // [buf][d][t^swz]

  int bid = blockIdx.x;
  int q   = bid >> 7;
  int b   = (bid >> 2) & 31;
  int n   = bid & 3;
  int tbase0 = q * 1152;
  const int NT = 18;

  int tid = threadIdx.x, lane = tid & 63, w = tid >> 6;
  int l5 = lane & 31;
  int hi = lane >> 5;            // 0 / 1
  int hi8 = hi * 8;
  int sq = w * 32 + l5;          // this lane's query row within SEQ

  // Q fragments (B-operand): lane holds Q[s=l5][k = ks*16 + hi*8 + j]
  v8s qf[8];
  {
    const unsigned short* qp = uvqk + (size_t)(b * SEQ + sq) * U_DIM
                               + 2 * D_HID + n * DHEAD + hi8;
#pragma unroll
    for (int ks = 0; ks < 8; ++ks) qf[ks] = *(const v8s*)(qp + ks * 16);
  }

  v16f oacc[4];
#pragma unroll
  for (int i = 0; i < 4; ++i)
#pragma unroll
    for (int r = 0; r < 16; ++r) oacc[i][r] = 0.f;

  int m     = tid & 15;
  int std0  = m * 8;            // staging d offset (8 contiguous)
  int strow = tid >> 4;         // staging t-pair index (0..31)

  const float* kbase = histK + (((size_t)b * HIST) * NHEAD + n) * DHEAD + std0;
  const float* vbase = histV + (((size_t)b * HIST) * NHEAD + n) * DHEAD + std0;
  const unsigned short* nkbase = uvqk + (size_t)(b * SEQ) * U_DIM + 3 * D_HID + n * DHEAD + std0;
  const unsigned short* nvbase = uvqk + (size_t)(b * SEQ) * U_DIM + 1 * D_HID + n * DHEAD + std0;

  // staging registers (next tile in flight)
  float4 hx[2][4];              // hist: [p][k0,k1,v0,v1]
  v8s    nx[2][2];              // new-kv: [p][k,v]
  int isnew_r = 0;

  auto stage_load = [&](int kt) {
    int tb = tbase0 + kt * 64;
    if (tb < HIST) {
      isnew_r = 0;
#pragma unroll
      for (int p = 0; p < 2; ++p) {
        unsigned off = ((unsigned)(tb + 2 * strow + p)) << 9;   // *512 floats
        hx[p][0] = *(const float4*)(kbase + off);
        hx[p][1] = *(const float4*)(kbase + off + 4);
        hx[p][2] = *(const float4*)(vbase + off);
        hx[p][3] = *(const float4*)(vbase + off + 4);
      }
    } else {
      isnew_r = 1;
#pragma unroll
      for (int p = 0; p < 2; ++p) {
        unsigned off = ((unsigned)(tb - HIST + 2 * strow + p)) << 11;  // *2048 shorts
        nx[p][0] = *(const v8s*)(nkbase + off);
        nx[p][1] = *(const v8s*)(nvbase + off);
      }
    }
  };

  auto stage_store = [&](int buf) {
    unsigned short* Kb = &Kl[buf * 8192];
    unsigned short* Vb = &Vt[buf * 8192];
    int t0 = 2 * strow;
    if (!isnew_r) {
#pragma unroll
      for (int p = 0; p < 2; ++p) {
        int t = t0 + p;
        v4u kp;
        kp[0] = cvtpk(hx[p][0].x, hx[p][0].y);
        kp[1] = cvtpk(hx[p][0].z, hx[p][0].w);
        kp[2] = cvtpk(hx[p][1].x, hx[p][1].y);
        kp[3] = cvtpk(hx[p][1].z, hx[p][1].w);
        *(v4u*)&Kb[t * 128 + (std0 ^ ((t & 7) << 3))] = kp;
      }
      float v0[8] = {hx[0][2].x, hx[0][2].y, hx[0][2].z, hx[0][2].w,
                     hx[0][3].x, hx[0][3].y, hx[0][3].z, hx[0][3].w};
      float v1[8] = {hx[1][2].x, hx[1][2].y, hx[1][2].z, hx[1][2].w,
                     hx[1][3].x, hx[1][3].y, hx[1][3].z, hx[1][3].w};
#pragma unroll
      for (int j = 0; j < 8; ++j) {
        int d = std0 + j;
        int col = t0 ^ ((((d >> 3) ^ d) & 7) << 3);
        *(unsigned int*)&Vb[d * 64 + col] = cvtpk(v0[j], v1[j]);
      }
    } else {
#pragma unroll
      for (int p = 0; p < 2; ++p) {
        int t = t0 + p;
        *(v8s*)&Kb[t * 128 + (std0 ^ ((t & 7) << 3))] = nx[p][0];
      }
#pragma unroll
      for (int j = 0; j < 8; ++j) {
        int d = std0 + j;
        int col = t0 ^ ((((d >> 3) ^ d) & 7) << 3);
        unsigned int pk = (unsigned int)(unsigned short)nx[0][1][j]
                        | ((unsigned int)(unsigned short)nx[1][1][j] << 16);
        *(unsigned int*)&Vb[d * 64 + col] = pk;
      }
    }
  };

  // prologue: tile 0 into buf0; tile 1 loaded to regs
  stage_load(0);
  stage_store(0);
  stage_load(1);
  __syncthreads();

  for (int kt = 0; kt < NT; ++kt) {
    int cur = kt & 1;
    if (kt + 1 < NT) stage_store(cur ^ 1);   // tile kt+1 -> other buffer
    if (kt + 2 < NT) stage_load(kt + 2);     // issue tile kt+2 global loads

    int tb = tbase0 + kt * 64;
    bool masked = (tb >= HIST);              // tile in new-token range
    const unsigned short* Kb = &Kl[cur * 8192];
    const unsigned short* Vb = &Vt[cur * 8192];

    __builtin_amdgcn_s_setprio(1);

    // ---- QK^T swapped (32x32x16): two interleaved chains (tt=0, tt=1) ----
    v8s pb[4];                               // PV B-fragments, ks = 0..3
    {
      v16f sa0, sa1;
#pragma unroll
      for (int r = 0; r < 16; ++r) { sa0[r] = 0.f; sa1[r] = 0.f; }
      int kx = (l5 & 7) << 3;                // same key for both tt rows
      int krow = l5 * 128;
#pragma unroll
      for (int ks = 0; ks < 8; ++ks) {
        int off = (ks * 16 + hi8) ^ kx;
        v8s kf0 = *(const v8s*)&Kb[krow + off];          // t row l5
        v8s kf1 = *(const v8s*)&Kb[krow + 4096 + off];   // t row 32+l5
        sa0 = __builtin_amdgcn_mfma_f32_32x32x16_bf16(kf0, qf[ks], sa0, 0, 0, 0);
        sa1 = __builtin_amdgcn_mfma_f32_32x32x16_bf16(kf1, qf[ks], sa1, 0, 0, 0);
      }
#pragma unroll
      for (int tt = 0; tt < 2; ++tt) {
        v16f sa = tt ? sa1 : sa0;
        unsigned e[8];
        if (masked) {
          int thr = sq - (tb - HIST) - tt * 32 - 4 * hi;   // keep if tl <= thr
#pragma unroll
          for (int i = 0; i < 8; ++i) {
            int r0 = 2 * i, r1 = 2 * i + 1;
            int tl0 = (r0 & 3) + 8 * (r0 >> 2);
            int tl1 = (r1 & 3) + 8 * (r1 >> 2);
            float p0 = (tl0 <= thr) ? siluf(sa[r0]) : 0.f;
            float p1 = (tl1 <= thr) ? siluf(sa[r1]) : 0.f;
            e[i] = cvtpk(p0, p1);
          }
        } else {
#pragma unroll
          for (int i = 0; i < 8; ++i) e[i] = cvtpk(siluf(sa[2 * i]), siluf(sa[2 * i + 1]));
        }
        // assemble PV B-fragments: lane needs t = hi*8 + j per k-step of 16
#pragma unroll
        for (int h = 0; h < 2; ++h) {
          unsigned a0 = e[h * 4 + 0], a1 = e[h * 4 + 1];
          unsigned b0 = e[h * 4 + 2], b1 = e[h * 4 + 3];
          unsigned sa0u = (unsigned)__shfl_xor((int)a0, 32, 64);
          unsigned sa1u = (unsigned)__shfl_xor((int)a1, 32, 64);
          unsigned sb0u = (unsigned)__shfl_xor((int)b0, 32, 64);
          unsigned sb1u = (unsigned)__shfl_xor((int)b1, 32, 64);
          union { unsigned u[4]; v8s s; } U;
          U.u[0] = hi ? sb0u : a0;
          U.u[1] = hi ? sb1u : a1;
          U.u[2] = hi ? b0 : sa0u;
          U.u[3] = hi ? b1 : sa1u;
          pb[tt * 2 + h] = U.s;
        }
      }
    }

    // ---- PV: oacc[d][s] += V^T . P^T  (A = Vt rows, B = pb, all in regs) ----
#pragma unroll
    for (int ks = 0; ks < 4; ++ks) {
#pragma unroll
      for (int dt4 = 0; dt4 < 4; ++dt4) {
        int d = dt4 * 32 + l5;
        int col = (ks * 16 + hi8) ^ ((((d >> 3) ^ d) & 7) << 3);
        v8s vf = *(const v8s*)&Vb[d * 64 + col];
        oacc[dt4] = __builtin_amdgcn_mfma_f32_32x32x16_bf16(vf, pb[ks], oacc[dt4], 0, 0, 0);
      }
    }
    __builtin_amdgcn_s_setprio(0);

    if (kt + 1 < NT) __syncthreads();       // buf^1 written by all; cur free
  }

  // ---- epilogue: D[d][s]: col = s = l5 (one q-row per lane), row = d via
  // (r&3)+8*(r>>2)+4*hi -> regs 4g..4g+3 are 4 consecutive d -> float4 ----
  {
    float* op = attn_out + (size_t)q * ((size_t)NTOK * D_HID)
              + (size_t)(b * SEQ + sq) * D_HID + n * DHEAD + 4 * hi;
#pragma unroll
    for (int dt4 = 0; dt4 < 4; ++dt4) {
#pragma unroll
      for (int g = 0; g < 4; ++g) {
        float4 o4 = make_float4(oacc[dt4][4 * g + 0], oacc[dt4][4 * g + 1],
                                oacc[dt4][4 * g + 2], oacc[dt4][4 * g + 3]);
        *(float4*)(op + dt4 * 32 + 8 * g) = o4;
      }
    }
  }
}

// ---------------------------------------------------------------------------
extern "C" void kernel_launch(void* const* d_in, const int* in_sizes, int n_in,
                              void* d_out, int out_size, void* d_ws, size_t ws_size,
                              hipStream_t stream)
{
  (void)in_sizes; (void)n_in; (void)out_size; (void)ws_size;

  const float* layer_input = (const float*)d_in[0];
  const float* hist_k   = (const float*)d_in[1];
  const float* hist_v   = (const float*)d_in[2];
  const float* ln_in_w  = (const float*)d_in[3];
  const float* ln_in_b  = (const float*)d_in[4];
  const float* W_uvqk   = (const float*)d_in[5];
  const float* b_uvqk   = (const float*)d_in[6];
  const float* ln_out_w = (const float*)d_in[7];
  const float* ln_out_b = (const float*)d_in[8];
  const float* W_proj   = (const float*)d_in[9];
  float* out = (float*)d_out;

  // workspace layout (x_bf dead after gemm1; attn1 written by attn -> share):
  char* ws = (char*)d_ws;
  unsigned short* uvqk    = (unsigned short*)(ws);                  // [ 0,32) MiB
  float*          attn0   = (float*)         (ws + (32u << 20));    // [32,48)
  float*          attn1   = (float*)         (ws + (48u << 20));    // [48,64)
  unsigned short* x_bf    = (unsigned short*)(ws + (48u << 20));    // [48,56) (dead before attn)
  unsigned short* par     = (unsigned short*)(ws + (64u << 20));    // [64,72)
  unsigned short* wt_uvqk = (unsigned short*)(ws + (72u << 20));    // [72,74)
  unsigned short* wt_proj = (unsigned short*)(ws + (74u << 20));    // [74,74.5)

  ln_in_kernel<<<dim3(2048), dim3(256), 0, stream>>>(layer_input, ln_in_w, ln_in_b, x_bf);
  transpose_w_kernel<<<dim3(64, 16), dim3(256), 0, stream>>>(W_uvqk, wt_uvqk, 512, 2048);
  transpose_w_kernel<<<dim3(16, 16), dim3(256), 0, stream>>>(W_proj, wt_proj, 512, 512);
  gemm_kernel<0><<<dim3(64, 16), dim3(256), 0, stream>>>(x_bf, wt_uvqk, 512, 2048,
                                                         b_uvqk, nullptr, uvqk, nullptr);
  attn_kernel<<<dim3(256), dim3(512), 0, stream>>>(hist_k, hist_v, uvqk, attn0);
  gated_ln_kernel<<<dim3(2048), dim3(256), 0, stream>>>(attn0, attn1, uvqk, ln_out_w, ln_out_b, par);
  gemm_kernel<1><<<dim3(64, 4), dim3(256), 0, stream>>>(par, wt_proj, 512, 512,
                                                        nullptr, layer_input, nullptr, out);
}